// Round 1
// 5823.308 us; speedup vs baseline: 1.7199x; 1.7199x over previous
//
#include <hip/hip_runtime.h>
#include <stdint.h>

// SequenceDecoder: B=128, EMB=512, H=1024, V=8192, T=100 (99 sequential steps).
// Design notes:
//  - argmax(log_softmax(x)) == argmax(x): recurrence only needs argmax of raw
//    logits. Raw logits go straight to d_out; one final kernel normalizes.
//  - Per-row (max,argmax) via packed u64 atomicMax during cls GEMM epilogue.
//  - GEMMs: fp16 hi/lo split (3 MFMA passes, lo scaled x2048) -> ~22 mantissa
//    bits. Split done inline while staging fp32 tiles to LDS.
//  - This version: 512-thread WGs (2 waves/SIMD), double-buffered LDS with
//    2-deep register prefetch and raw s_barrier + manual lgkmcnt(0) (keeps
//    global loads in flight across barriers; __syncthreads would drain vmcnt).
//  - GRU elementwise fused into k_gates epilogue via split-K ticket: last
//    arriving of the 4 K-range WGs per colgroup sums partials + writes hnew.
//    2 kernels per step instead of 3.

#define Bb   128
#define EMBd 512
#define Hd   1024
#define Vd   8192
#define Td   100

typedef __attribute__((ext_vector_type(8))) _Float16 half8;
typedef __attribute__((ext_vector_type(4))) float f32x4;
typedef unsigned long long ull;

#define LOSCALE 2048.0f
#define LOINV   (1.0f/2048.0f)
#define PADK    40   // LDS row stride in fp16 elems (32 data + 8 pad; 80B, 16B-aligned)

__device__ __forceinline__ uint32_t fkey(float f) {
  uint32_t u = __float_as_uint(f);
  return (u & 0x80000000u) ? ~u : (u | 0x80000000u);
}
__device__ __forceinline__ ull umax64(ull a, ull b) { return a > b ? a : b; }

// convert 8 fp32 (2 float4 regs) into fp16 hi + (lo*2048), store to LDS
__device__ __forceinline__ void cvt8(const float4 v0, const float4 v1,
                                     _Float16* dh, _Float16* dl) {
  float vv[8] = {v0.x, v0.y, v0.z, v0.w, v1.x, v1.y, v1.z, v1.w};
  half8 hh, ll;
#pragma unroll
  for (int i = 0; i < 8; ++i) {
    _Float16 h = (_Float16)vv[i];
    hh[i] = h;
    ll[i] = (_Float16)((vv[i] - (float)h) * LOSCALE);
  }
  *(half8*)dh = hh;
  *(half8*)dl = ll;
}

// ---------------------------------------------------------------- init
__global__ void k_init(const float* __restrict__ x, float* __restrict__ hbuf0,
                       ull* __restrict__ amax, int* __restrict__ ticket) {
  int tid = blockIdx.x * 256 + threadIdx.x;
  if (tid < Bb * Hd) hbuf0[tid] = x[tid];
  if (tid < Td * Bb) amax[tid] = (tid < Bb) ? 0xFFFFFFFFull : 0ull;  // t=0: idx=0
  if (tid < 64) ticket[tid] = 0;
}

// ------------------------------------- gates GEMM (+ fused GRU elementwise)
// grid (64, 4): x = colgroup (16 cols of H), y = q (combined-K range of 384).
// Combined K: [0,512) = e-part (A = emb[idx]), [512,1536) = h-part (A = h_prev).
// part layout: [q][cg][gate6][row128][col16] fp32. Gates 0..2 = i_{r,z,n},
// 3..5 = h_{r,z,n}. The 4th-arriving WG per cg (device-scope ticket) sums the
// 4 partial slabs, applies the GRU cell, writes hnew[:, cg*16 .. cg*16+16).
__global__ __launch_bounds__(512) void k_gates(
    const float* __restrict__ emb, const float* __restrict__ w_ih,
    const float* __restrict__ w_hh, const float* __restrict__ hprev,
    const ull* __restrict__ amax_prev,
    const float* __restrict__ b_ih, const float* __restrict__ b_hh,
    float* __restrict__ hnew, float* __restrict__ part,
    int* __restrict__ ticket)
{
  const int cg = blockIdx.x;
  const int q  = blockIdx.y;
  const int tid = threadIdx.x;
  const int lane = tid & 63;
  const int w = tid >> 6;          // wave 0..7 -> rows [w*16, w*16+16)
  const int C = cg * 16;

  __shared__ _Float16 Ah[2][128 * PADK];
  __shared__ _Float16 Al[2][128 * PADK];
  __shared__ _Float16 Bh[2][48 * PADK];
  __shared__ _Float16 Bl[2][48 * PADK];
  __shared__ int sidx[128];
  __shared__ int swin;

  if (tid < 128) sidx[tid] = (int)((~(uint32_t)amax_prev[tid]) & 8191u);
  __syncthreads();

  f32x4 accH[6], accL[6];
#pragma unroll
  for (int g = 0; g < 6; ++g) {
    accH[g] = (f32x4){0.f, 0.f, 0.f, 0.f};
    accL[g] = (f32x4){0.f, 0.f, 0.f, 0.f};
  }

  // staging map: A: all 512 threads, 8 floats each (128 rows x 32 k).
  //              B: threads 0..191, 8 floats each (48 rows x 32 k).
  const int arow  = tid >> 2;
  const int akoff = (tid & 3) * 8;
  const int brow  = tid >> 2;            // valid for tid < 192
  const int bg    = brow >> 4, bn = brow & 15;
  const int bkoff = (tid & 3) * 8;
  const int aidx  = sidx[arow];          // emb row for e-part
  const float* bbase_e = w_ih + (size_t)(bg * 1024 + C + bn) * EMBd;
  const float* bbase_h = w_hh + (size_t)(bg * 1024 + C + bn) * Hd;

  float4 pA0, pA1, pB0, pB1;
  auto issue = [&](int st) {
    const int k0 = q * 384 + st * 32;
    const bool eph = (k0 < 512);
    const float* sa = eph ? (emb + (size_t)aidx * EMBd + (k0 + akoff))
                          : (hprev + (size_t)arow * Hd + (k0 - 512 + akoff));
    pA0 = *(const float4*)sa;
    pA1 = *(const float4*)(sa + 4);
    if (tid < 192) {
      const float* sb = eph ? (bbase_e + k0 + bkoff) : (bbase_h + (k0 - 512 + bkoff));
      pB0 = *(const float4*)sb;
      pB1 = *(const float4*)(sb + 4);
    }
  };
  auto cvtstore = [&](int st) {
    const int b = st & 1;
    cvt8(pA0, pA1, &Ah[b][arow * PADK + akoff], &Al[b][arow * PADK + akoff]);
    if (tid < 192) cvt8(pB0, pB1, &Bh[b][brow * PADK + bkoff], &Bl[b][brow * PADK + bkoff]);
  };

  issue(0);
  cvtstore(0);
  issue(1);

  for (int st = 0; st < 12; ++st) {
    asm volatile("s_waitcnt lgkmcnt(0)" ::: "memory");
    __builtin_amdgcn_s_barrier();
    const int b = st & 1;
    const bool eph = (q * 384 + st * 32) < 512;
    const int gbase = eph ? 0 : 3;

    const int aoff = (w * 16 + (lane & 15)) * PADK + (lane >> 4) * 8;
    half8 aH = *(half8*)&Ah[b][aoff];
    half8 aL = *(half8*)&Al[b][aoff];
#pragma unroll
    for (int g = 0; g < 3; ++g) {
      const int boff = (g * 16 + (lane & 15)) * PADK + (lane >> 4) * 8;
      half8 bH = *(half8*)&Bh[b][boff];
      half8 bL = *(half8*)&Bl[b][boff];
      accH[gbase + g] = __builtin_amdgcn_mfma_f32_16x16x32_f16(aH, bH, accH[gbase + g], 0, 0, 0);
      accL[gbase + g] = __builtin_amdgcn_mfma_f32_16x16x32_f16(aH, bL, accL[gbase + g], 0, 0, 0);
      accL[gbase + g] = __builtin_amdgcn_mfma_f32_16x16x32_f16(aL, bH, accL[gbase + g], 0, 0, 0);
    }
    if (st + 1 < 12) {
      cvtstore(st + 1);
      if (st + 2 < 12) issue(st + 2);
    }
  }

  // store partials: D layout col=lane&15, row=(lane>>4)*4+i [m89]
  float* base = part + (size_t)(q * 64 + cg) * 6 * 2048;
  const int q4 = (lane >> 4) * 4, cl = lane & 15;
#pragma unroll
  for (int gs = 0; gs < 6; ++gs) {
    const int row = w * 16 + q4;
#pragma unroll
    for (int i = 0; i < 4; ++i)
      base[gs * 2048 + (row + i) * 16 + cl] = accH[gs][i] + accL[gs][i] * LOINV;
  }

  // ---- split-K ticket: last WG of the 4 q-ranges does the GRU for this cg
  __syncthreads();                       // drains vmcnt -> partials in L2
  if (tid == 0) {
    __threadfence();                     // writeback to coherence point (LLC)
    int old = __hip_atomic_fetch_add(&ticket[cg], 1, __ATOMIC_ACQ_REL,
                                     __HIP_MEMORY_SCOPE_AGENT);
    swin = (old == 3);
  }
  __syncthreads();
  if (!swin) return;

  // winner: acquire (cache inv) done by tid0's RMW; all waves same CU/XCD.
#pragma unroll
  for (int k = 0; k < 4; ++k) {
    const int e2 = tid + k * 512;        // 0..2047
    const int r = e2 >> 4, c = e2 & 15;
    const int j = C + c;
    float g[6] = {0.f, 0.f, 0.f, 0.f, 0.f, 0.f};
#pragma unroll
    for (int q2 = 0; q2 < 4; ++q2) {
      const float* p = part + (size_t)(q2 * 64 + cg) * 6 * 2048 + r * 16 + c;
#pragma unroll
      for (int gs = 0; gs < 6; ++gs) g[gs] += p[gs * 2048];
    }
    float ir = g[0] + b_ih[j], iz = g[1] + b_ih[1024 + j], in_ = g[2] + b_ih[2048 + j];
    float hr = g[3] + b_hh[j], hz = g[4] + b_hh[1024 + j], hn = g[5] + b_hh[2048 + j];
    float rr = 1.f / (1.f + expf(-(ir + hr)));
    float zz = 1.f / (1.f + expf(-(iz + hz)));
    float nn = tanhf(in_ + rr * hn);
    hnew[r * Hd + j] = (1.f - zz) * nn + zz * hprev[r * Hd + j];
  }
  if (tid == 0)
    __hip_atomic_store(&ticket[cg], 0, __ATOMIC_RELAXED, __HIP_MEMORY_SCOPE_AGENT);
}

// ----------------------------------------------- cls GEMM + argmax atomics
// grid (128, 2): 64-col x 64-row tiles. 8 waves: wr in {0,1} (32 rows),
// wc in {0..3} (16 cols). Double-buffered LDS, 2-deep prefetch.
__global__ __launch_bounds__(512) void k_cls(
    const float* __restrict__ h, const float* __restrict__ cls_w,
    const float* __restrict__ cls_b, float* __restrict__ out,
    ull* __restrict__ amax_s, int s)
{
  const int ct = blockIdx.x, rt0 = blockIdx.y;
  const int tid = threadIdx.x, lane = tid & 63, w = tid >> 6;
  const int wr = w >> 2, wc = w & 3;
  const int r0 = rt0 * 64, c0 = ct * 64;

  __shared__ _Float16 Ah[2][64 * PADK], Al[2][64 * PADK];
  __shared__ _Float16 Bh[2][64 * PADK], Bl[2][64 * PADK];
  __shared__ ull cand[64][4];

  f32x4 accH[2], accL[2];
#pragma unroll
  for (int i = 0; i < 2; ++i) {
    accH[i] = (f32x4){0.f, 0.f, 0.f, 0.f};
    accL[i] = (f32x4){0.f, 0.f, 0.f, 0.f};
  }

  // staging: threads 0..255 -> A (h rows), threads 256..511 -> B (cls_w rows)
  const int srow = (tid & 255) >> 2;     // 0..63
  const int skoff = (tid & 3) * 8;
  const bool isB = tid >= 256;
  const float* sbase = isB ? (cls_w + (size_t)(c0 + srow) * Hd)
                           : (h + (size_t)(r0 + srow) * Hd);

  float4 p0, p1;
  auto issue = [&](int st) {
    const float* src = sbase + st * 32 + skoff;
    p0 = *(const float4*)src;
    p1 = *(const float4*)(src + 4);
  };
  auto cvtstore = [&](int st) {
    const int b = st & 1;
    _Float16* dh = isB ? &Bh[b][srow * PADK + skoff] : &Ah[b][srow * PADK + skoff];
    _Float16* dl = isB ? &Bl[b][srow * PADK + skoff] : &Al[b][srow * PADK + skoff];
    cvt8(p0, p1, dh, dl);
  };

  issue(0);
  cvtstore(0);
  issue(1);

  for (int st = 0; st < 32; ++st) {
    asm volatile("s_waitcnt lgkmcnt(0)" ::: "memory");
    __builtin_amdgcn_s_barrier();
    const int b = st & 1;
    half8 aH[2], aL[2];
#pragma unroll
    for (int i = 0; i < 2; ++i) {
      const int aoff = (wr * 32 + i * 16 + (lane & 15)) * PADK + (lane >> 4) * 8;
      aH[i] = *(half8*)&Ah[b][aoff];
      aL[i] = *(half8*)&Al[b][aoff];
    }
    const int boff = (wc * 16 + (lane & 15)) * PADK + (lane >> 4) * 8;
    half8 bH = *(half8*)&Bh[b][boff];
    half8 bL = *(half8*)&Bl[b][boff];
#pragma unroll
    for (int i = 0; i < 2; ++i) {
      accH[i] = __builtin_amdgcn_mfma_f32_16x16x32_f16(aH[i], bH, accH[i], 0, 0, 0);
      accL[i] = __builtin_amdgcn_mfma_f32_16x16x32_f16(aH[i], bL, accL[i], 0, 0, 0);
      accL[i] = __builtin_amdgcn_mfma_f32_16x16x32_f16(aL[i], bH, accL[i], 0, 0, 0);
    }
    if (st + 1 < 32) {
      cvtstore(st + 1);
      if (st + 2 < 32) issue(st + 2);
    }
  }

  // epilogue: +bias, store raw logits, packed (max,argmax) -> atomicMax
  const int qq = lane >> 4, cl = lane & 15;
  const int v = c0 + wc * 16 + cl;
  const float bias = cls_b[v];
#pragma unroll
  for (int rt = 0; rt < 2; ++rt) {
    ull best[4];
#pragma unroll
    for (int i = 0; i < 4; ++i) {
      float val = accH[rt][i] + accL[rt][i] * LOINV + bias;
      const int brow = r0 + wr * 32 + rt * 16 + qq * 4 + i;
      out[((size_t)brow * Td + s) * Vd + v] = val;
      best[i] = ((ull)fkey(val) << 32) | (uint32_t)(~(uint32_t)v);
    }
#pragma unroll
    for (int i = 0; i < 4; ++i) {
      ull bb = best[i];
      bb = umax64(bb, __shfl_xor(bb, 1));
      bb = umax64(bb, __shfl_xor(bb, 2));
      bb = umax64(bb, __shfl_xor(bb, 4));
      bb = umax64(bb, __shfl_xor(bb, 8));
      if (cl == 0) cand[wr * 32 + rt * 16 + qq * 4 + i][wc] = bb;
    }
  }
  __syncthreads();
  if (tid < 64) {
    ull m_ = umax64(umax64(cand[tid][0], cand[tid][1]),
                    umax64(cand[tid][2], cand[tid][3]));
    atomicMax(&amax_s[r0 + tid], m_);
  }
}

// -------------------------------------------------- final log_softmax pass
__global__ void k_softmax(float* __restrict__ out,
                          const ull* __restrict__ amax) {
  int blk = blockIdx.x;           // 12800 = 128*100
  int t = blk % Td, b = blk / Td;
  int tid = threadIdx.x;
  float* row = out + ((size_t)b * Td + t) * Vd;
  if (t == 0) {
    float lse0 = logf(expf(1.0f) + (float)(Vd - 1));
    for (int i = tid; i < Vd; i += 256) row[i] = ((i == 0) ? 1.0f : 0.0f) - lse0;
    return;
  }
  ull key = amax[t * Bb + b];
  uint32_t ku = (uint32_t)(key >> 32);
  uint32_t u = (ku & 0x80000000u) ? (ku & 0x7fffffffu) : ~ku;
  float m = __uint_as_float(u);     // exact row max (same fp32 bits as stored)
  float x[32];
  float ssum = 0.f;
#pragma unroll
  for (int i = 0; i < 32; ++i) {
    x[i] = row[tid + i * 256];
    ssum += expf(x[i] - m);
  }
  ssum += __shfl_xor(ssum, 1);
  ssum += __shfl_xor(ssum, 2);
  ssum += __shfl_xor(ssum, 4);
  ssum += __shfl_xor(ssum, 8);
  ssum += __shfl_xor(ssum, 16);
  ssum += __shfl_xor(ssum, 32);
  __shared__ float wsum[4];
  if ((tid & 63) == 0) wsum[tid >> 6] = ssum;
  __syncthreads();
  float lse = m + logf(wsum[0] + wsum[1] + wsum[2] + wsum[3]);
#pragma unroll
  for (int i = 0; i < 32; ++i) row[tid + i * 256] = x[i] - lse;
}

// ----------------------------------------------------------------- launch
extern "C" void kernel_launch(void* const* d_in, const int* in_sizes, int n_in,
                              void* d_out, int out_size, void* d_ws, size_t ws_size,
                              hipStream_t stream) {
  const float* x     = (const float*)d_in[0];
  const float* emb   = (const float*)d_in[1];
  const float* w_ih  = (const float*)d_in[2];
  const float* w_hh  = (const float*)d_in[3];
  const float* b_ih  = (const float*)d_in[4];
  const float* b_hh  = (const float*)d_in[5];
  const float* cls_w = (const float*)d_in[6];
  const float* cls_b = (const float*)d_in[7];
  float* out = (float*)d_out;

  char* ws = (char*)d_ws;
  ull*   amax   = (ull*)ws;                                     // 100*128*8 = 102400 B
  float* hbuf   = (float*)(ws + 102400);                        // 2*128*1024*4 = 1 MB
  float* part   = (float*)(ws + 102400 + 2 * Bb * Hd * 4);      // 4*64*6*2048*4 = 12.6 MB
  int*   ticket = (int*)(ws + 102400 + 2 * Bb * Hd * 4 + 4 * 64 * 6 * 2048 * 4);  // 256 B

  k_init<<<512, 256, 0, stream>>>(x, hbuf, amax, ticket);
  for (int s = 1; s < Td; ++s) {
    const float* hp = hbuf + (size_t)((s - 1) & 1) * Bb * Hd;
    float* hn = hbuf + (size_t)(s & 1) * Bb * Hd;
    k_gates<<<dim3(64, 4), 512, 0, stream>>>(emb, w_ih, w_hh, hp,
                                             amax + (size_t)(s - 1) * Bb,
                                             b_ih, b_hh, hn, part, ticket);
    k_cls<<<dim3(128, 2), 512, 0, stream>>>(hn, cls_w, cls_b, out,
                                            amax + (size_t)s * Bb, s);
  }
  k_softmax<<<12800, 256, 0, stream>>>(out, amax);
}

// Round 2
// 5270.450 us; speedup vs baseline: 1.9003x; 1.1049x over previous
//
#include <hip/hip_runtime.h>
#include <stdint.h>

// SequenceDecoder: B=128, EMB=512, H=1024, V=8192, T=100 (99 sequential steps).
//  - argmax(log_softmax) == argmax(raw): recurrence needs only raw-logit argmax.
//  - fp16 hi/lo split GEMMs (3 MFMA passes, lo x2048) ~22 mantissa bits.
//  - NEW: weights pre-converted ONCE to fp16 hi|lo tile images with the LDS
//    XOR-swizzle (chunk ^= row&7) baked into the global layout. All K-loop
//    staging is global_load_lds width-16 DMA (incl. the embedding gather via
//    per-lane inverse-swizzled source addresses). Triple-buffered LDS,
//    counted vmcnt (never 0 mid-loop), raw s_barrier.
//  - GRU fused into k_gates via split-K ticket; winner also emits h as a
//    pre-swizzled fp16 tile for the next GEMMs.

#define Bb   128
#define EMBd 512
#define Hd   1024
#define Vd   8192
#define Td   100

typedef __attribute__((ext_vector_type(8))) _Float16 half8;
typedef __attribute__((ext_vector_type(4))) float f32x4;
typedef unsigned long long ull;

#define LOSCALE 2048.0f
#define LOINV   (1.0f/2048.0f)

__device__ __forceinline__ uint32_t fkey(float f) {
  uint32_t u = __float_as_uint(f);
  return (u & 0x80000000u) ? ~u : (u | 0x80000000u);
}
__device__ __forceinline__ ull umax64(ull a, ull b) { return a > b ? a : b; }

__device__ __forceinline__ void dma16(const void* g, void* l) {
  __builtin_amdgcn_global_load_lds((const uint32_t*)g, (uint32_t*)l, 16, 0, 0);
}

// split 8 fp32 into fp16 hi + (lo*2048)
__device__ __forceinline__ void cvt8(const float4 v0, const float4 v1,
                                     half8& hh, half8& ll) {
  float vv[8] = {v0.x, v0.y, v0.z, v0.w, v1.x, v1.y, v1.z, v1.w};
#pragma unroll
  for (int i = 0; i < 8; ++i) {
    _Float16 h = (_Float16)vv[i];
    hh[i] = h;
    ll[i] = (_Float16)((vv[i] - (float)h) * LOSCALE);
  }
}

// ---------------------------------------------------------------- init
// also converts x -> hpre0 swizzled fp16 tile [st32][b128][8 chunks of 16B]
__global__ void k_init(const float* __restrict__ x, float* __restrict__ hbuf0,
                       ull* __restrict__ amax, int* __restrict__ ticket,
                       char* __restrict__ hpre0) {
  int tid = blockIdx.x * 256 + threadIdx.x;
  if (tid < Bb * Hd) hbuf0[tid] = x[tid];
  if (tid < Td * Bb) amax[tid] = (tid < Bb) ? 0xFFFFFFFFull : 0ull;  // t=0: idx=0
  if (tid < 64) ticket[tid] = 0;
  if (tid < 16384) {
    int b = tid & 127, sc = tid >> 7;
    int st = sc >> 2, c = sc & 3;
    const float* src = x + b * Hd + st * 32 + c * 8;
    float4 v0 = *(const float4*)src, v1 = *(const float4*)(src + 4);
    half8 hh, ll; cvt8(v0, v1, hh, ll);
    char* hp = hpre0 + st * 16384 + b * 128;
    *(half8*)(hp + ((c       ^ (b & 7))) * 16) = hh;
    *(half8*)(hp + (((c + 4) ^ (b & 7))) * 16) = ll;
  }
}

// ------------------------------------------------------------- prep kernels
// emb_pre: [row 8192][st_e 16][chunk 8][16B], UNSWIZZLED (swizzle applied via
// per-lane DMA source index at gather time, since LDS row = batch, not emb row)
__global__ void k_prep_emb(const float* __restrict__ emb, char* __restrict__ embp) {
  int t = blockIdx.x * 256 + threadIdx.x;          // 524288 total
  int row = t >> 6, rem = t & 63, st = rem >> 2, c = rem & 3;
  const float* src = emb + (size_t)row * EMBd + st * 32 + c * 8;
  float4 v0 = *(const float4*)src, v1 = *(const float4*)(src + 4);
  half8 hh, ll; cvt8(v0, v1, hh, ll);
  char* d = embp + (size_t)row * 2048 + st * 128;
  *(half8*)(d + c * 16) = hh;
  *(half8*)(d + (c + 4) * 16) = ll;
}

// wpre: per (cg,q,st) tile: [48 rows][128B], swizzled (chunk ^= r&7)
__global__ void k_prep_w(const float* __restrict__ w_ih, const float* __restrict__ w_hh,
                         char* __restrict__ wpre) {
  int bi = blockIdx.x;                 // (cg*4+q)*12+st, 3072 blocks
  int st = bi % 12, t2 = bi / 12, q = t2 & 3, cg = t2 >> 2;
  int t = threadIdx.x; if (t >= 192) return;
  int r = t >> 2, c = t & 3;
  int g = r >> 4, bn = r & 15;
  int k0 = q * 384 + st * 32 + c * 8;
  const float* src = (k0 < 512)
    ? (w_ih + (size_t)(g * 1024 + cg * 16 + bn) * EMBd + k0)
    : (w_hh + (size_t)(g * 1024 + cg * 16 + bn) * Hd + (k0 - 512));
  float4 v0 = *(const float4*)src, v1 = *(const float4*)(src + 4);
  half8 hh, ll; cvt8(v0, v1, hh, ll);
  char* d = wpre + (size_t)bi * 6144 + r * 128;
  *(half8*)(d + ((c       ^ (r & 7))) * 16) = hh;
  *(half8*)(d + (((c + 4) ^ (r & 7))) * 16) = ll;
}

// clspre: [ct 128][st 32][64 rows][128B], swizzled
__global__ void k_prep_cls(const float* __restrict__ cls_w, char* __restrict__ clsp) {
  int b = blockIdx.x;                  // ct*32+st, 4096 blocks
  int ct = b >> 5, st = b & 31;
  int t = threadIdx.x;
  int r = t >> 2, c = t & 3;
  const float* src = cls_w + (size_t)(ct * 64 + r) * Hd + st * 32 + c * 8;
  float4 v0 = *(const float4*)src, v1 = *(const float4*)(src + 4);
  half8 hh, ll; cvt8(v0, v1, hh, ll);
  char* d = clsp + (size_t)b * 8192 + r * 128;
  *(half8*)(d + ((c       ^ (r & 7))) * 16) = hh;
  *(half8*)(d + (((c + 4) ^ (r & 7))) * 16) = ll;
}

// ------------------------------------- gates GEMM (+ fused GRU elementwise)
// grid (64,4): cg = 16 cols of H, q = combined-K range of 384 (e:[0,512) h:[512,1536)).
// All staging = DMA: 2 A-ops + 1 B-op per wave per iter, depth-3 LDS.
__global__ __launch_bounds__(512) void k_gates(
    const char* __restrict__ embp, const char* __restrict__ wpre,
    const char* __restrict__ hpre_prev,
    const ull* __restrict__ amax_prev,
    const float* __restrict__ b_ih, const float* __restrict__ b_hh,
    const float* __restrict__ hprev_f, float* __restrict__ hnew_f,
    char* __restrict__ hpre_new,
    float* __restrict__ part, int* __restrict__ ticket)
{
  const int cg = blockIdx.x, q = blockIdx.y;
  const int tid = threadIdx.x, lane = tid & 63, w = tid >> 6;
  const int C = cg * 16;

  __shared__ __align__(16) char Ab[3][128 * 128];
  __shared__ __align__(16) char Bt[3][48 * 128];
  __shared__ int swin;

  // DMA source setup. A-op o covers rows w*16+o*8 .. +8; lane = (rowoff<<3)|chunk.
  const int rlo = lane >> 3, c1 = lane & 7;
  const int b0 = w * 16 + rlo;
  const uint32_t sid0 = (~(uint32_t)amax_prev[b0]) & 8191u;
  const uint32_t sid1 = (~(uint32_t)amax_prev[b0 + 8]) & 8191u;
  const int cswz = (c1 ^ rlo) * 16;        // (b&7)==rlo for both rows
  const char* esrc0 = embp + (size_t)sid0 * 2048 + cswz;
  const char* esrc1 = embp + (size_t)sid1 * 2048 + cswz;
  const char* hsrc  = hpre_prev + w * 2048 + lane * 16;
  const char* bsrc  = wpre + (size_t)((cg * 4 + q) * 12) * 6144 + w * 768 + lane * 16;
  // force sidx loads consumed before first DMA so counted vmcnt stays exact
  asm volatile("" :: "v"(esrc0), "v"(esrc1));

  f32x4 accH[6], accL[6];
#pragma unroll
  for (int g = 0; g < 6; ++g) {
    accH[g] = (f32x4){0.f, 0.f, 0.f, 0.f};
    accL[g] = (f32x4){0.f, 0.f, 0.f, 0.f};
  }

  auto issue = [&](int st) {
    char* da = &Ab[st % 3][w * 2048];
    const int k0 = q * 384 + st * 32;
    if (k0 < 512) {
      const int o = (k0 >> 5) * 128;
      dma16(esrc0 + o, da);
      dma16(esrc1 + o, da + 1024);
    } else {
      const char* sp = hsrc + ((k0 - 512) >> 5) * 16384;
      dma16(sp, da);
      dma16(sp + 1024, da + 1024);
    }
    if (lane < 48) dma16(bsrc + st * 6144, &Bt[st % 3][w * 768]);
  };

  const int l15 = lane & 15, qd = lane >> 4, r7 = l15 & 7;
  const int offAH = (w * 16 + l15) * 128 + ((qd)     ^ r7) * 16;
  const int offAL = (w * 16 + l15) * 128 + ((qd + 4) ^ r7) * 16;
  const int offBH = l15 * 128 + ((qd)     ^ r7) * 16;
  const int offBL = l15 * 128 + ((qd + 4) ^ r7) * 16;

  issue(0); issue(1);
  asm volatile("s_waitcnt vmcnt(3)" ::: "memory");
  __builtin_amdgcn_sched_barrier(0);
  __builtin_amdgcn_s_barrier();

#define GATE3(GB)                                                              \
  _Pragma("unroll")                                                            \
  for (int g = 0; g < 3; ++g) {                                                \
    half8 bH = *(half8*)&Bt[bf][g * 2048 + offBH];                             \
    half8 bL = *(half8*)&Bt[bf][g * 2048 + offBL];                             \
    accH[GB + g] = __builtin_amdgcn_mfma_f32_16x16x32_f16(aH, bH, accH[GB + g], 0, 0, 0); \
    accL[GB + g] = __builtin_amdgcn_mfma_f32_16x16x32_f16(aH, bL, accL[GB + g], 0, 0, 0); \
    accL[GB + g] = __builtin_amdgcn_mfma_f32_16x16x32_f16(aL, bH, accL[GB + g], 0, 0, 0); \
  }

  for (int st = 0; st < 12; ++st) {
    const int bf = st % 3;
    const bool eph = (q * 384 + st * 32) < 512;
    half8 aH = *(half8*)&Ab[bf][offAH];
    half8 aL = *(half8*)&Ab[bf][offAL];
    if (st + 2 < 12) issue(st + 2);
    if (eph) { GATE3(0) } else { GATE3(3) }
    if (st < 11) {
      if (st < 10) asm volatile("s_waitcnt vmcnt(3)" ::: "memory");
      else         asm volatile("s_waitcnt vmcnt(0)" ::: "memory");
      __builtin_amdgcn_sched_barrier(0);
      asm volatile("s_waitcnt lgkmcnt(0)" ::: "memory");
      __builtin_amdgcn_sched_barrier(0);
      __builtin_amdgcn_s_barrier();
    }
  }
#undef GATE3

  // store partials: D layout col=lane&15, row=(lane>>4)*4+i [m89]
  {
    float* base = part + (size_t)(q * 64 + cg) * 6 * 2048;
    const int q4 = (lane >> 4) * 4, cl = lane & 15;
    const int row = w * 16 + q4;
#pragma unroll
    for (int gs = 0; gs < 6; ++gs)
#pragma unroll
      for (int i = 0; i < 4; ++i)
        base[gs * 2048 + (row + i) * 16 + cl] = accH[gs][i] + accL[gs][i] * LOINV;
  }

  __syncthreads();
  if (tid == 0) {
    __threadfence();
    int old = __hip_atomic_fetch_add(&ticket[cg], 1, __ATOMIC_ACQ_REL,
                                     __HIP_MEMORY_SCOPE_AGENT);
    swin = (old == 3);
  }
  __syncthreads();
  if (!swin) return;

  // winner: sum 4 q-partials, GRU, write hnew fp32 + swizzled fp16 tile
  if (tid < 256) {
    const int b = tid >> 1, hf = tid & 1;
    const int j0 = C + hf * 8;
    float gv[6][8];
#pragma unroll
    for (int gs = 0; gs < 6; ++gs)
#pragma unroll
      for (int i = 0; i < 8; ++i) gv[gs][i] = 0.f;
    for (int q2 = 0; q2 < 4; ++q2) {
      const float* p = part + (size_t)(q2 * 64 + cg) * 6 * 2048 + b * 16 + hf * 8;
#pragma unroll
      for (int gs = 0; gs < 6; ++gs)
#pragma unroll
        for (int i = 0; i < 8; ++i) gv[gs][i] += p[gs * 2048 + i];
    }
    float outs[8];
#pragma unroll
    for (int i = 0; i < 8; ++i) {
      const int j = j0 + i;
      float ir = gv[0][i] + b_ih[j], iz = gv[1][i] + b_ih[1024 + j], in_ = gv[2][i] + b_ih[2048 + j];
      float hr = gv[3][i] + b_hh[j], hz = gv[4][i] + b_hh[1024 + j], hn = gv[5][i] + b_hh[2048 + j];
      float rr = 1.f / (1.f + expf(-(ir + hr)));
      float zz = 1.f / (1.f + expf(-(iz + hz)));
      float nn = tanhf(in_ + rr * hn);
      outs[i] = (1.f - zz) * nn + zz * hprev_f[b * Hd + j];
    }
    *(float4*)(hnew_f + b * Hd + j0)     = (float4){outs[0], outs[1], outs[2], outs[3]};
    *(float4*)(hnew_f + b * Hd + j0 + 4) = (float4){outs[4], outs[5], outs[6], outs[7]};
    half8 hh, ll;
#pragma unroll
    for (int i = 0; i < 8; ++i) {
      _Float16 h = (_Float16)outs[i];
      hh[i] = h; ll[i] = (_Float16)((outs[i] - (float)h) * LOSCALE);
    }
    const int stp = j0 >> 5;             // == cg>>1
    const int chi = (j0 & 31) >> 3;      // 0..3
    char* hp = hpre_new + stp * 16384 + b * 128;
    *(half8*)(hp + ((chi       ^ (b & 7))) * 16) = hh;
    *(half8*)(hp + (((chi + 4) ^ (b & 7))) * 16) = ll;
  }
  if (tid == 0)
    __hip_atomic_store(&ticket[cg], 0, __ATOMIC_RELAXED, __HIP_MEMORY_SCOPE_AGENT);
}

// ----------------------------------------------- cls GEMM + argmax atomics
// grid (128,2): 64x64 tiles, 8 waves (wr{0,1} x wc{0..3}). All-DMA staging,
// 2 ops/wave/iter, depth-3 LDS, counted vmcnt.
__global__ __launch_bounds__(512) void k_cls(
    const char* __restrict__ hpre, const char* __restrict__ clsp,
    const float* __restrict__ cls_b, float* __restrict__ out,
    ull* __restrict__ amax_s, int s)
{
  const int ct = blockIdx.x, rt0 = blockIdx.y;
  const int tid = threadIdx.x, lane = tid & 63, w = tid >> 6;
  const int wr = w >> 2, wc = w & 3;
  const int r0 = rt0 * 64, c0 = ct * 64;

  __shared__ __align__(16) char Ab[3][8192];
  __shared__ __align__(16) char Bt[3][8192];
  __shared__ ull cand[64][4];

  f32x4 accH[2], accL[2];
#pragma unroll
  for (int i = 0; i < 2; ++i) {
    accH[i] = (f32x4){0.f, 0.f, 0.f, 0.f};
    accL[i] = (f32x4){0.f, 0.f, 0.f, 0.f};
  }

  const char* asrc = hpre + rt0 * 8192 + w * 1024 + lane * 16;           // +st*16384
  const char* bsrc = clsp + (size_t)ct * 262144 + w * 1024 + lane * 16;  // +st*8192

  auto issue = [&](int st) {
    dma16(asrc + st * 16384, &Ab[st % 3][w * 1024]);
    dma16(bsrc + st * 8192,  &Bt[st % 3][w * 1024]);
  };

  const int l15 = lane & 15, qd = lane >> 4, r7 = l15 & 7;
  const int offAH = (wr * 32 + l15) * 128 + ((qd)     ^ r7) * 16;
  const int offAL = (wr * 32 + l15) * 128 + ((qd + 4) ^ r7) * 16;
  const int offBH = (wc * 16 + l15) * 128 + ((qd)     ^ r7) * 16;
  const int offBL = (wc * 16 + l15) * 128 + ((qd + 4) ^ r7) * 16;

  issue(0); issue(1);
  asm volatile("s_waitcnt vmcnt(2)" ::: "memory");
  __builtin_amdgcn_sched_barrier(0);
  __builtin_amdgcn_s_barrier();

  for (int st = 0; st < 32; ++st) {
    const int bf = st % 3;
    half8 aH0 = *(half8*)&Ab[bf][offAH];
    half8 aL0 = *(half8*)&Ab[bf][offAL];
    half8 aH1 = *(half8*)&Ab[bf][offAH + 2048];
    half8 aL1 = *(half8*)&Ab[bf][offAL + 2048];
    half8 bH  = *(half8*)&Bt[bf][offBH];
    half8 bL  = *(half8*)&Bt[bf][offBL];
    if (st + 2 < 32) issue(st + 2);
    accH[0] = __builtin_amdgcn_mfma_f32_16x16x32_f16(aH0, bH, accH[0], 0, 0, 0);
    accL[0] = __builtin_amdgcn_mfma_f32_16x16x32_f16(aH0, bL, accL[0], 0, 0, 0);
    accL[0] = __builtin_amdgcn_mfma_f32_16x16x32_f16(aL0, bH, accL[0], 0, 0, 0);
    accH[1] = __builtin_amdgcn_mfma_f32_16x16x32_f16(aH1, bH, accH[1], 0, 0, 0);
    accL[1] = __builtin_amdgcn_mfma_f32_16x16x32_f16(aH1, bL, accL[1], 0, 0, 0);
    accL[1] = __builtin_amdgcn_mfma_f32_16x16x32_f16(aL1, bH, accL[1], 0, 0, 0);
    if (st < 31) {
      if (st < 30) asm volatile("s_waitcnt vmcnt(2)" ::: "memory");
      else         asm volatile("s_waitcnt vmcnt(0)" ::: "memory");
      __builtin_amdgcn_sched_barrier(0);
      asm volatile("s_waitcnt lgkmcnt(0)" ::: "memory");
      __builtin_amdgcn_sched_barrier(0);
      __builtin_amdgcn_s_barrier();
    }
  }

  // epilogue: +bias, store raw logits, packed (max,argmax) -> atomicMax
  const int qq = lane >> 4, cl = lane & 15;
  const int v = c0 + wc * 16 + cl;
  const float bias = cls_b[v];
#pragma unroll
  for (int rt = 0; rt < 2; ++rt) {
    ull best[4];
#pragma unroll
    for (int i = 0; i < 4; ++i) {
      float val = accH[rt][i] + accL[rt][i] * LOINV + bias;
      const int brow = r0 + wr * 32 + rt * 16 + qq * 4 + i;
      out[((size_t)brow * Td + s) * Vd + v] = val;
      best[i] = ((ull)fkey(val) << 32) | (uint32_t)(~(uint32_t)v);
    }
#pragma unroll
    for (int i = 0; i < 4; ++i) {
      ull bb = best[i];
      bb = umax64(bb, __shfl_xor(bb, 1));
      bb = umax64(bb, __shfl_xor(bb, 2));
      bb = umax64(bb, __shfl_xor(bb, 4));
      bb = umax64(bb, __shfl_xor(bb, 8));
      if (cl == 0) cand[wr * 32 + rt * 16 + qq * 4 + i][wc] = bb;
    }
  }
  __syncthreads();
  if (tid < 64) {
    ull m_ = umax64(umax64(cand[tid][0], cand[tid][1]),
                    umax64(cand[tid][2], cand[tid][3]));
    atomicMax(&amax_s[r0 + tid], m_);
  }
}

// -------------------------------------------------- final log_softmax pass
__global__ void k_softmax(float* __restrict__ out,
                          const ull* __restrict__ amax) {
  int blk = blockIdx.x;           // 12800 = 128*100
  int t = blk % Td, b = blk / Td;
  int tid = threadIdx.x;
  float* row = out + ((size_t)b * Td + t) * Vd;
  if (t == 0) {
    float lse0 = logf(expf(1.0f) + (float)(Vd - 1));
    for (int i = tid; i < Vd; i += 256) row[i] = ((i == 0) ? 1.0f : 0.0f) - lse0;
    return;
  }
  ull key = amax[t * Bb + b];
  uint32_t ku = (uint32_t)(key >> 32);
  uint32_t u = (ku & 0x80000000u) ? (ku & 0x7fffffffu) : ~ku;
  float m = __uint_as_float(u);
  float x[32];
  float ssum = 0.f;
#pragma unroll
  for (int i = 0; i < 32; ++i) {
    x[i] = row[tid + i * 256];
    ssum += expf(x[i] - m);
  }
  ssum += __shfl_xor(ssum, 1);
  ssum += __shfl_xor(ssum, 2);
  ssum += __shfl_xor(ssum, 4);
  ssum += __shfl_xor(ssum, 8);
  ssum += __shfl_xor(ssum, 16);
  ssum += __shfl_xor(ssum, 32);
  __shared__ float wsum[4];
  if ((tid & 63) == 0) wsum[tid >> 6] = ssum;
  __syncthreads();
  float lse = m + logf(wsum[0] + wsum[1] + wsum[2] + wsum[3]);
#pragma unroll
  for (int i = 0; i < 32; ++i) row[tid + i * 256] = x[i] - lse;
}

// ----------------------------------------------------------------- launch
extern "C" void kernel_launch(void* const* d_in, const int* in_sizes, int n_in,
                              void* d_out, int out_size, void* d_ws, size_t ws_size,
                              hipStream_t stream) {
  const float* x     = (const float*)d_in[0];
  const float* emb   = (const float*)d_in[1];
  const float* w_ih  = (const float*)d_in[2];
  const float* w_hh  = (const float*)d_in[3];
  const float* b_ih  = (const float*)d_in[4];
  const float* b_hh  = (const float*)d_in[5];
  const float* cls_w = (const float*)d_in[6];
  const float* cls_b = (const float*)d_in[7];
  float* out = (float*)d_out;

  char* ws = (char*)d_ws;
  size_t o = 0;
  ull*   amax   = (ull*)(ws + o);   o += (size_t)Td * Bb * 8;        // 100 KB
  int*   ticket = (int*)(ws + o);   o += 1024;
  float* hbuf   = (float*)(ws + o); o += (size_t)2 * Bb * Hd * 4;    // 1 MB
  float* part   = (float*)(ws + o); o += (size_t)4 * 64 * 6 * 2048 * 4; // 12.6 MB
  char*  hpre   = ws + o;           o += (size_t)2 * 32 * Bb * 128;  // 1 MB
  char*  embp   = ws + o;           o += (size_t)Vd * 2048;          // 16.8 MB
  char*  wpre   = ws + o;           o += (size_t)3072 * 6144;        // 18.9 MB
  char*  clsp   = ws + o;           o += (size_t)128 * 32 * 8192;    // 33.6 MB

  k_init<<<512, 256, 0, stream>>>(x, hbuf, amax, ticket, hpre);
  k_prep_emb<<<2048, 256, 0, stream>>>(emb, embp);
  k_prep_w<<<3072, 256, 0, stream>>>(w_ih, w_hh, wpre);
  k_prep_cls<<<4096, 256, 0, stream>>>(cls_w, clsp);

  for (int s = 1; s < Td; ++s) {
    const float* hpf = hbuf + (size_t)((s - 1) & 1) * Bb * Hd;
    float* hnf = hbuf + (size_t)(s & 1) * Bb * Hd;
    const char* hpp = hpre + (size_t)((s - 1) & 1) * 32 * Bb * 128;
    char* hpn = hpre + (size_t)(s & 1) * 32 * Bb * 128;
    k_gates<<<dim3(64, 4), 512, 0, stream>>>(embp, wpre, hpp,
                                             amax + (size_t)(s - 1) * Bb,
                                             b_ih, b_hh, hpf, hnf, hpn, part, ticket);
    k_cls<<<dim3(128, 2), 512, 0, stream>>>(hpn, clsp, cls_b, out,
                                            amax + (size_t)s * Bb, s);
  }
  k_softmax<<<12800, 256, 0, stream>>>(out, amax);
}